// Round 1
// baseline (428.424 us; speedup 1.0000x reference)
//
#include <hip/hip_runtime.h>

// x: (4, 4096, 4096) fp32. Row = 4096 = 32 heads x 128 dims.
// out[b,s,h*128+d] = (1/sqrt(32)) * sum_{h'} (-1)^popcount(h&h') x[b,s,h'*128+d]
// i.e. 32-pt FWHT across heads for each dim d, per row.
//
// One thread handles one row and 4 consecutive dims (one float4 per head).
// 32 float4 loads (stride 32 float4) -> 5-stage in-register FWHT -> 32 float4 stores.

#define NUM_HEADS 32
#define ROW_F4 1024   // 4096 floats / 4
#define HEAD_F4 32    // 128 floats / 4

__global__ __launch_bounds__(256) void fwht_heads_kernel(
    const float* __restrict__ x, float* __restrict__ out, int num_rows) {
    int tid = blockIdx.x * blockDim.x + threadIdx.x;
    int d4 = tid & 31;              // which group of 4 dims (0..31)
    long long row = tid >> 5;       // which row (b*4096+s)
    if (row >= num_rows) return;

    const float4* __restrict__ xp = (const float4*)x + row * ROW_F4 + d4;
    float4* __restrict__ op = (float4*)out + row * ROW_F4 + d4;

    float4 v[NUM_HEADS];
#pragma unroll
    for (int h = 0; h < NUM_HEADS; ++h) {
        v[h] = xp[h * HEAD_F4];
    }

    // in-register FWHT over the head index (5 butterfly stages)
#pragma unroll
    for (int s = 1; s < NUM_HEADS; s <<= 1) {
#pragma unroll
        for (int i = 0; i < NUM_HEADS; ++i) {
            if ((i & s) == 0) {
                int j = i | s;
                float4 a = v[i];
                float4 b = v[j];
                v[i] = make_float4(a.x + b.x, a.y + b.y, a.z + b.z, a.w + b.w);
                v[j] = make_float4(a.x - b.x, a.y - b.y, a.z - b.z, a.w - b.w);
            }
        }
    }

    const float scale = 0.17677669529663687f;  // 1/sqrt(32)
#pragma unroll
    for (int h = 0; h < NUM_HEADS; ++h) {
        float4 a = v[h];
        op[h * HEAD_F4] =
            make_float4(a.x * scale, a.y * scale, a.z * scale, a.w * scale);
    }
}

extern "C" void kernel_launch(void* const* d_in, const int* in_sizes, int n_in,
                              void* d_out, int out_size, void* d_ws, size_t ws_size,
                              hipStream_t stream) {
    const float* x = (const float*)d_in[0];
    float* out = (float*)d_out;

    int total = in_sizes[0];          // 4*4096*4096 = 67108864
    int num_rows = total / 4096;      // 16384
    int threads = num_rows * 32;      // one thread per (row, dim-group-of-4)

    dim3 block(256);
    dim3 grid((threads + 255) / 256);
    fwht_heads_kernel<<<grid, block, 0, stream>>>(x, out, num_rows);
}

// Round 2
// 426.943 us; speedup vs baseline: 1.0035x; 1.0035x over previous
//
#include <hip/hip_runtime.h>

// x: (4, 4096, 4096) fp32. Row = 4096 = 32 heads x 128 dims.
// out[b,s,h*128+d] = (1/sqrt(32)) * sum_{h'} (-1)^popcount(h&h') x[b,s,h'*128+d]
// 32-pt FWHT across heads for each dim d, per row.
//
// Thread layout: 128 threads per row. r = t & 127; j = r & 3 (head mod 4),
// d4 = r >> 2 (dim-group of 4 floats, 0..31). Each thread holds the 8 heads
// {j, j+4, ..., j+28} for its dim-group: 8 float4 = 32 data VGPRs.
// FWHT stages 4/8/16 are in-register (partner head in same thread);
// stages 1/2 are __shfl_xor lane^1 / lane^2 (j = lane&3, so in-wave).

__global__ __launch_bounds__(256) void fwht_heads_shfl(
    const float4* __restrict__ x, float4* __restrict__ out, int total_threads) {
    int t = blockIdx.x * blockDim.x + threadIdx.x;
    if (t >= total_threads) return;
    int row = t >> 7;          // 128 threads per row
    int r = t & 127;
    int j = r & 3;             // head mod 4 -> shuffle partner = lane^1, lane^2
    int d4 = r >> 2;           // dim-group 0..31

    int base = row * 1024 + j * 32 + d4;   // float4 index
    const float4* __restrict__ xp = x + base;

    float4 v[8];               // v[k] = head j + 4k
#pragma unroll
    for (int k = 0; k < 8; ++k) v[k] = xp[k * 128];

    // stages s=4,8,16 over head -> stride 1,2,4 over k (in-register)
#pragma unroll
    for (int s = 1; s < 8; s <<= 1) {
#pragma unroll
        for (int k = 0; k < 8; ++k) {
            if ((k & s) == 0) {
                int m = k | s;
                float4 a = v[k], b = v[m];
                v[k] = make_float4(a.x + b.x, a.y + b.y, a.z + b.z, a.w + b.w);
                v[m] = make_float4(a.x - b.x, a.y - b.y, a.z - b.z, a.w - b.w);
            }
        }
    }

    // stages s=1 (lane^1, sign from j&1) and s=2 (lane^2, sign from j&2)
    float sg1 = (j & 1) ? -1.0f : 1.0f;
    float sg2 = (j & 2) ? -1.0f : 1.0f;
#pragma unroll
    for (int k = 0; k < 8; ++k) {
        float4 o = v[k];
        float4 p;
        p.x = __shfl_xor(o.x, 1);
        p.y = __shfl_xor(o.y, 1);
        p.z = __shfl_xor(o.z, 1);
        p.w = __shfl_xor(o.w, 1);
        o = make_float4(sg1 * o.x + p.x, sg1 * o.y + p.y,
                        sg1 * o.z + p.z, sg1 * o.w + p.w);
        p.x = __shfl_xor(o.x, 2);
        p.y = __shfl_xor(o.y, 2);
        p.z = __shfl_xor(o.z, 2);
        p.w = __shfl_xor(o.w, 2);
        v[k] = make_float4(sg2 * o.x + p.x, sg2 * o.y + p.y,
                           sg2 * o.z + p.z, sg2 * o.w + p.w);
    }

    const float scale = 0.17677669529663687f;  // 1/sqrt(32)
    float4* __restrict__ op = out + base;
#pragma unroll
    for (int k = 0; k < 8; ++k) {
        float4 a = v[k];
        op[k * 128] = make_float4(a.x * scale, a.y * scale,
                                  a.z * scale, a.w * scale);
    }
}

extern "C" void kernel_launch(void* const* d_in, const int* in_sizes, int n_in,
                              void* d_out, int out_size, void* d_ws, size_t ws_size,
                              hipStream_t stream) {
    const float4* x = (const float4*)d_in[0];
    float4* out = (float4*)d_out;

    int total = in_sizes[0];              // 67108864 floats
    int num_rows = total / 4096;          // 16384
    int total_threads = num_rows * 128;   // 2097152

    dim3 block(256);
    dim3 grid((total_threads + 255) / 256);
    fwht_heads_shfl<<<grid, block, 0, stream>>>(x, out, total_threads);
}